// Round 1
// 292.961 us; speedup vs baseline: 1.0591x; 1.0591x over previous
//
#include <hip/hip_runtime.h>
#include <math.h>

constexpr int cE = 8;
constexpr int cH = 1024;
constexpr int cF = 2816;
constexpr int cR = 256;
constexpr int cT = 2048;
constexpr int ROWS = cT * 2;   // total routed (token, expert) rows = T*K
constexpr int LDA = 40;        // padded LDS row stride (BK=32 reg-staged kernels)

using short8  = __attribute__((ext_vector_type(8))) short;
using float4v = __attribute__((ext_vector_type(4))) float;
#define MFMA16 __builtin_amdgcn_mfma_f32_16x16x32_bf16

__device__ __forceinline__ unsigned short f2bf(float f) {
  union { float f; unsigned u; } v; v.f = f;
  unsigned r = v.u + 0x7fffu + ((v.u >> 16) & 1u);   // RNE
  return (unsigned short)(r >> 16);
}
__device__ __forceinline__ float bf2f(unsigned short s) {
  union { unsigned u; float f; } v; v.u = (unsigned)s << 16; return v.f;
}

// pack 8 fp32 -> 8 bf16, single 16B store
__device__ __forceinline__ void store_bf8(unsigned short* dst, float4 a, float4 b) {
  union { unsigned short u[8]; uint4 v; } t;
  t.u[0] = f2bf(a.x); t.u[1] = f2bf(a.y); t.u[2] = f2bf(a.z); t.u[3] = f2bf(a.w);
  t.u[4] = f2bf(b.x); t.u[5] = f2bf(b.y); t.u[6] = f2bf(b.z); t.u[7] = f2bf(b.w);
  *reinterpret_cast<uint4*>(dst) = t.v;
}

// async global->LDS, 16 B per lane. LDS dest = wave-uniform base + lane*16,
// global source address is per-lane (gather-capable).
__device__ __forceinline__ void gld16(const unsigned short* g, unsigned short* l) {
  __builtin_amdgcn_global_load_lds(
      (const __attribute__((address_space(1))) void*)g,
      (__attribute__((address_space(3))) void*)l, 16, 0, 0);
}

// ---------------------------------------------------------------------------
// gating (wave-per-token) + x->bf16 conversion fused.
// ---------------------------------------------------------------------------
__global__ __launch_bounds__(256) void k_gating(
    const float* __restrict__ x, const float* __restrict__ gw,
    unsigned short* __restrict__ xb, int* __restrict__ et,
    float* __restrict__ wt)
{
  const int tid = threadIdx.x;
  const int wid = tid >> 6, lane = tid & 63;
  const int t = blockIdx.x * 4 + wid;
  const float* xr = x + (long)t * cH + lane * 16;
  float4 v0 = *reinterpret_cast<const float4*>(xr);
  float4 v1 = *reinterpret_cast<const float4*>(xr + 4);
  float4 v2 = *reinterpret_cast<const float4*>(xr + 8);
  float4 v3 = *reinterpret_cast<const float4*>(xr + 12);
  store_bf8(xb + (long)t * cH + lane * 16, v0, v1);
  store_bf8(xb + (long)t * cH + lane * 16 + 8, v2, v3);
  float xv[16];
  *reinterpret_cast<float4*>(&xv[0])  = v0;
  *reinterpret_cast<float4*>(&xv[4])  = v1;
  *reinterpret_cast<float4*>(&xv[8])  = v2;
  *reinterpret_cast<float4*>(&xv[12]) = v3;
  const float* g = gw + (long)lane * 16 * cE;
  float l[cE];
#pragma unroll
  for (int e = 0; e < cE; ++e) l[e] = 0.f;
#pragma unroll
  for (int i = 0; i < 16; ++i) {
    float4 ga = *reinterpret_cast<const float4*>(g + i * cE);
    float4 gb = *reinterpret_cast<const float4*>(g + i * cE + 4);
    float xi = xv[i];
    l[0] += xi * ga.x; l[1] += xi * ga.y; l[2] += xi * ga.z; l[3] += xi * ga.w;
    l[4] += xi * gb.x; l[5] += xi * gb.y; l[6] += xi * gb.z; l[7] += xi * gb.w;
  }
#pragma unroll
  for (int m = 1; m < 64; m <<= 1)
#pragma unroll
    for (int e = 0; e < cE; ++e)
      l[e] += __shfl_xor(l[e], m, 64);
  if (lane == 0) {
    int i0 = 0; float m0 = l[0];
#pragma unroll
    for (int e = 1; e < cE; ++e) if (l[e] > m0) { m0 = l[e]; i0 = e; }
    int i1 = -1; float m1 = -1e30f;
#pragma unroll
    for (int e = 0; e < cE; ++e) if (e != i0 && l[e] > m1) { m1 = l[e]; i1 = e; }
    float w0 = 1.f / (1.f + expf(m1 - m0));
    et[t * 2 + 0] = i0;  et[t * 2 + 1] = i1;
    wt[t * 2 + 0] = w0;  wt[t * 2 + 1] = 1.f - w0;
  }
}

// ---------------------------------------------------------------------------
// build compact per-expert token lists + inverse map (single block).
// rowmap: (token,slot) -> compact row; tok: compact row -> token.
// ---------------------------------------------------------------------------
__global__ __launch_bounds__(256) void k_lists(
    const int* __restrict__ et, int* __restrict__ rowmap,
    int* __restrict__ tok, int* __restrict__ cnt, int* __restrict__ off)
{
  __shared__ int c[cE], p[cE], o[cE];
  const int tid = threadIdx.x;
  if (tid < cE) { c[tid] = 0; p[tid] = 0; }
  __syncthreads();
  for (int i = tid; i < ROWS; i += 256) atomicAdd(&c[et[i]], 1);
  __syncthreads();
  if (tid == 0) {
    int s = 0;
    for (int e = 0; e < cE; ++e) { o[e] = s; s += c[e]; }
  }
  __syncthreads();
  for (int i = tid; i < ROWS; i += 256) {
    int e = et[i];
    int slot = atomicAdd(&p[e], 1);
    int cr = o[e] + slot;
    rowmap[i] = cr;
    tok[cr] = i >> 1;
  }
  if (tid < cE) { cnt[tid] = c[tid]; off[tid] = o[tid]; }
}

// ---------------------------------------------------------------------------
// transpose + fp32->bf16 tile body: in [P][Q] per batch -> out [Q][P]
// ---------------------------------------------------------------------------
__device__ __forceinline__ void tconv_tile(
    const float* __restrict__ in, unsigned short* __restrict__ out,
    int P, int Q, int e, int bx, int by, int tid, float (*tile)[33])
{
  const long es = (long)P * Q;
  in += e * es; out += e * es;
  const int c0 = bx * 32, r0 = by * 32;
  const int r = tid >> 3, c4 = (tid & 7) * 4;
  float4 v = *reinterpret_cast<const float4*>(in + (long)(r0 + r) * Q + c0 + c4);
  tile[r][c4 + 0] = v.x; tile[r][c4 + 1] = v.y;
  tile[r][c4 + 2] = v.z; tile[r][c4 + 3] = v.w;
  __syncthreads();
  const int cc = tid >> 3, rr4 = (tid & 7) * 4;
  ushort4 o;
  o.x = f2bf(tile[rr4 + 0][cc]);
  o.y = f2bf(tile[rr4 + 1][cc]);
  o.z = f2bf(tile[rr4 + 2][cc]);
  o.w = f2bf(tile[rr4 + 3][cc]);
  *reinterpret_cast<ushort4*>(out + (long)(c0 + cc) * P + r0 + rr4) = o;
}

// All 6 transposes in ONE launch (static shapes -> compile-time block ranges).
//  [0,64)      Cg  256x256 x1
//  [64,128)    Cu  256x256 x1
//  [128,2176)  Vd  256x1024 x8
//  [2176,7808) Vg  256x2816 x8
//  [7808,13440)Vu  256x2816 x8
//  [13440,19072) Ud 2816x256 x8
constexpr int TCONV_BLOCKS = 19072;
__global__ __launch_bounds__(256) void k_tconv_all(
    const float* __restrict__ Cg, unsigned short* __restrict__ CgT,
    const float* __restrict__ Cu, unsigned short* __restrict__ CuT,
    const float* __restrict__ Vd, unsigned short* __restrict__ VdT,
    const float* __restrict__ Vg, unsigned short* __restrict__ vgT,
    const float* __restrict__ Vu, unsigned short* __restrict__ vuT,
    const float* __restrict__ Ud, unsigned short* __restrict__ udT)
{
  __shared__ float tile[32][33];
  int b = blockIdx.x;
  const float* in; unsigned short* out; int P, Q;
  if (b < 64)         { in = Cg; out = CgT; P = 256;  Q = 256;  }
  else if (b < 128)   { b -= 64;    in = Cu; out = CuT; P = 256;  Q = 256;  }
  else if (b < 2176)  { b -= 128;   in = Vd; out = VdT; P = 256;  Q = 1024; }
  else if (b < 7808)  { b -= 2176;  in = Vg; out = vgT; P = 256;  Q = 2816; }
  else if (b < 13440) { b -= 7808;  in = Vu; out = vuT; P = 256;  Q = 2816; }
  else                { b -= 13440; in = Ud; out = udT; P = 2816; Q = 256;  }
  const int tpe = (P / 32) * (Q / 32);
  const int e = b / tpe, rem = b % tpe;
  const int bx = rem % (Q / 32), by = rem / (Q / 32);
  tconv_tile(in, out, P, Q, e, bx, by, threadIdx.x, tile);
}

// ---------------------------------------------------------------------------
// MFMA fold body: D[m][n] = sum_k A[m][k] * B[n][k],  K = 256 fixed.
// tile 128x64, BK=32, register prefetch.
// ---------------------------------------------------------------------------
__device__ __forceinline__ void foldm_body(
    const unsigned short* __restrict__ A, const float* __restrict__ B,
    unsigned short* __restrict__ D, int ldd, int m0, int n0, int tid,
    unsigned short* As, unsigned short* Bs)
{
  const int sr = tid >> 2, sk = (tid & 3) * 8;
  const unsigned short* a0 = A + (long)(m0 + sr) * 256 + sk;
  const unsigned short* a1 = a0 + (long)64 * 256;
  const float* br = B + (long)(n0 + sr) * 256 + sk;
  uint4 rA0, rA1; float4 rB0, rB1;
  auto load_slice = [&](int k0) {
    rA0 = *reinterpret_cast<const uint4*>(a0 + k0);
    rA1 = *reinterpret_cast<const uint4*>(a1 + k0);
    rB0 = *reinterpret_cast<const float4*>(br + k0);
    rB1 = *reinterpret_cast<const float4*>(br + k0 + 4);
  };
  load_slice(0);
  const int wid = tid >> 6, lane = tid & 63;
  const int wm = (wid >> 1) * 64, wn = (wid & 1) * 32;
  const int fr = lane & 15, fq = lane >> 4;
  float4v zf = {0.f, 0.f, 0.f, 0.f};
  float4v acc[4][2];
#pragma unroll
  for (int i = 0; i < 4; ++i) { acc[i][0] = zf; acc[i][1] = zf; }
  for (int k0 = 0; k0 < 256; k0 += 32) {
    *reinterpret_cast<uint4*>(&As[sr * LDA + sk]) = rA0;
    *reinterpret_cast<uint4*>(&As[(sr + 64) * LDA + sk]) = rA1;
    store_bf8(&Bs[sr * LDA + sk], rB0, rB1);
    if (k0 + 32 < 256) load_slice(k0 + 32);
    __syncthreads();
    short8 af[4], bf[2];
#pragma unroll
    for (int mi = 0; mi < 4; ++mi)
      af[mi] = *reinterpret_cast<const short8*>(&As[(wm + mi * 16 + fr) * LDA + fq * 8]);
#pragma unroll
    for (int nj = 0; nj < 2; ++nj)
      bf[nj] = *reinterpret_cast<const short8*>(&Bs[(wn + nj * 16 + fr) * LDA + fq * 8]);
#pragma unroll
    for (int mi = 0; mi < 4; ++mi)
#pragma unroll
      for (int nj = 0; nj < 2; ++nj)
        acc[mi][nj] = MFMA16(af[mi], bf[nj], acc[mi][nj], 0, 0, 0);
    __syncthreads();
  }
#pragma unroll
  for (int mi = 0; mi < 4; ++mi)
#pragma unroll
    for (int r = 0; r < 4; ++r) {
      int m = m0 + wm + mi * 16 + fq * 4 + r;
#pragma unroll
      for (int nj = 0; nj < 2; ++nj)
        D[(long)m * ldd + n0 + wn + nj * 16 + fr] = f2bf(acc[mi][nj][r]);
    }
}

// vd2t fold (generic, per-expert strides). grid = (N/64, M/128, E)
__global__ __launch_bounds__(256, 2) void k_foldm(
    const unsigned short* __restrict__ A, long sA,
    const float* __restrict__ B, long sB,
    unsigned short* __restrict__ D, long sD, int ldd)
{
  __shared__ __align__(16) unsigned short As[128 * LDA], Bs[64 * LDA];
  const int e = blockIdx.z;
  foldm_body(A + e * sA, B + e * sB, D + e * sD, ldd,
             blockIdx.y * 128, blockIdx.x * 64, threadIdx.x, As, Bs);
}

// merged gate+up b1t fold: z = sel<<3 | e. grid = (cH/64, cR/128, 16)
__global__ __launch_bounds__(256, 2) void k_foldm2(
    const unsigned short* __restrict__ A0, const unsigned short* __restrict__ A1,
    const float* __restrict__ B0, const float* __restrict__ B1,
    unsigned short* __restrict__ D)
{
  __shared__ __align__(16) unsigned short As[128 * LDA], Bs[64 * LDA];
  const int z = blockIdx.z, sel = z >> 3, e = z & 7;
  const unsigned short* A = sel ? A1 : A0;
  const float* B = (sel ? B1 : B0) + (long)e * cH * cR;
  unsigned short* Dp = D + (long)e * 512 * 1024 + (long)sel * 256 * 1024;
  foldm_body(A, B, Dp, cH, blockIdx.y * 128, blockIdx.x * 64, threadIdx.x, As, Bs);
}

// ---------------------------------------------------------------------------
// COMPACT t1 GEMM: t1[o+row] = xb[tok[o+row]] @ b1t[e]^T   (K=1024, N=512)
// Only the routed (token,expert) rows are computed (4.3 GF vs 17.2 GF dense).
// tile 128x64, BK=64, gather via per-lane global_load_lds source addresses.
// grid = (512/64, cT/128, E), early-return past cnt[e].
// ---------------------------------------------------------------------------
__global__ __launch_bounds__(256, 2) void k_t1c(
    const unsigned short* __restrict__ xb, const unsigned short* __restrict__ b1t,
    unsigned short* __restrict__ t1, const int* __restrict__ tok,
    const int* __restrict__ cnt, const int* __restrict__ off)
{
  __shared__ __align__(16) unsigned short As[128 * 64], Bs[64 * 64];
  const int e = blockIdx.z, c = cnt[e], o = off[e];
  const int m0 = blockIdx.y * 128;
  if (m0 >= c) return;
  const int n0 = blockIdx.x * 64;
  const int tid = threadIdx.x;
  const int wid = tid >> 6, lane = tid & 63;
  const int sr8 = lane >> 3, sc = (lane & 7) * 8;
  // A: 128 gathered rows; wave stages rows [wid*32, wid*32+32), 8 rows/gld16
  const unsigned short* gA[4];
#pragma unroll
  for (int j = 0; j < 4; ++j) {
    int row = min(m0 + wid * 32 + j * 8 + sr8, c - 1);
    gA[j] = xb + (long)tok[o + row] * cH + sc;
  }
  // B: 64 rows of b1t[e]; wave stages rows [wid*16, wid*16+16)
  const unsigned short* gB = b1t + (long)e * 512 * 1024 +
      (long)(n0 + wid * 16 + sr8) * 1024 + sc;
  unsigned short* lA = As + wid * 32 * 64;   // wave-uniform dest
  unsigned short* lB = Bs + wid * 16 * 64;
  const int wm = (wid >> 1) * 64, wn = (wid & 1) * 32;
  const int fr = lane & 15, fq = lane >> 4;
  float4v zf = {0.f, 0.f, 0.f, 0.f};
  float4v acc[4][2];
#pragma unroll
  for (int i = 0; i < 4; ++i) { acc[i][0] = zf; acc[i][1] = zf; }
  for (int k0 = 0; k0 < cH; k0 += 64) {
#pragma unroll
    for (int j = 0; j < 4; ++j) gld16(gA[j] + k0, lA + j * 8 * 64);
    gld16(gB + k0, lB);
    gld16(gB + (long)8 * 1024 + k0, lB + 8 * 64);
    __syncthreads();
#pragma unroll
    for (int ks = 0; ks < 2; ++ks) {
      short8 af[4], bf[2];
#pragma unroll
      for (int mi = 0; mi < 4; ++mi)
        af[mi] = *reinterpret_cast<const short8*>(
            &As[(wm + mi * 16 + fr) * 64 + ks * 32 + fq * 8]);
#pragma unroll
      for (int nj = 0; nj < 2; ++nj)
        bf[nj] = *reinterpret_cast<const short8*>(
            &Bs[(wn + nj * 16 + fr) * 64 + ks * 32 + fq * 8]);
#pragma unroll
      for (int mi = 0; mi < 4; ++mi)
#pragma unroll
        for (int nj = 0; nj < 2; ++nj)
          acc[mi][nj] = MFMA16(af[mi], bf[nj], acc[mi][nj], 0, 0, 0);
    }
    __syncthreads();
  }
#pragma unroll
  for (int mi = 0; mi < 4; ++mi)
#pragma unroll
    for (int r = 0; r < 4; ++r) {
      int row = m0 + wm + mi * 16 + fq * 4 + r;
      if (row < c) {
#pragma unroll
        for (int nj = 0; nj < 2; ++nj)
          t1[(long)(o + row) * 512 + n0 + wn + nj * 16 + fr] = f2bf(acc[mi][nj][r]);
      }
    }
}

// ---------------------------------------------------------------------------
// dual GEMM: a = silu(t1g @ vgT^T) * (t1u @ vuT^T)  [rows x F], K=256
// async staging, unpadded LDS, BK=32, clamped staging rows. grid=(44,16,E)
// ---------------------------------------------------------------------------
__global__ __launch_bounds__(256, 2) void k_act(
    const unsigned short* __restrict__ t1,
    const unsigned short* __restrict__ vgT, const unsigned short* __restrict__ vuT,
    unsigned short* __restrict__ a, const int* __restrict__ cnt,
    const int* __restrict__ off)
{
  __shared__ __align__(16) unsigned short Ag[128 * 32], Au[128 * 32];
  __shared__ __align__(16) unsigned short Bg[64 * 32],  Bu[64 * 32];
  const int e = blockIdx.z, c = cnt[e], o = off[e];
  const int m0 = blockIdx.y * 128;
  if (m0 >= c) return;
  const int n0 = blockIdx.x * 64;
  const int tid = threadIdx.x;
  const int wid = tid >> 6, lane = tid & 63;
  const int sr16 = lane >> 2, sc = (lane & 3) * 8;
  const int ra0 = o + min(m0 + wid * 32 + sr16, c - 1);
  const int ra1 = o + min(m0 + wid * 32 + 16 + sr16, c - 1);
  const unsigned short* gAg0 = t1 + (long)ra0 * 512 + sc;
  const unsigned short* gAg1 = t1 + (long)ra1 * 512 + sc;
  const unsigned short* gBg = vgT + (long)e * cF * 256 + (long)(n0 + wid * 16 + sr16) * 256 + sc;
  const unsigned short* gBu = vuT + (long)e * cF * 256 + (long)(n0 + wid * 16 + sr16) * 256 + sc;
  unsigned short* lAg = Ag + wid * 32 * 32;
  unsigned short* lAu = Au + wid * 32 * 32;
  unsigned short* lBg = Bg + wid * 16 * 32;
  unsigned short* lBu = Bu + wid * 16 * 32;
  const int wm = (wid >> 1) * 64, wn = (wid & 1) * 32;
  const int fr = lane & 15, fq = lane >> 4;
  float4v zf = {0.f, 0.f, 0.f, 0.f};
  float4v accg[4][2], accu[4][2];
#pragma unroll
  for (int i = 0; i < 4; ++i) { accg[i][0] = zf; accg[i][1] = zf; accu[i][0] = zf; accu[i][1] = zf; }
  for (int k0 = 0; k0 < 256; k0 += 32) {
    gld16(gAg0 + k0, lAg);
    gld16(gAg1 + k0, lAg + 16 * 32);
    gld16(gAg0 + 256 + k0, lAu);
    gld16(gAg1 + 256 + k0, lAu + 16 * 32);
    gld16(gBg + k0, lBg);
    gld16(gBu + k0, lBu);
    __syncthreads();
    short8 ag[4], au[4], bg[2], bu[2];
#pragma unroll
    for (int mi = 0; mi < 4; ++mi) {
      ag[mi] = *reinterpret_cast<const short8*>(&Ag[(wm + mi * 16 + fr) * 32 + fq * 8]);
      au[mi] = *reinterpret_cast<const short8*>(&Au[(wm + mi * 16 + fr) * 32 + fq * 8]);
    }
#pragma unroll
    for (int nj = 0; nj < 2; ++nj) {
      bg[nj] = *reinterpret_cast<const short8*>(&Bg[(wn + nj * 16 + fr) * 32 + fq * 8]);
      bu[nj] = *reinterpret_cast<const short8*>(&Bu[(wn + nj * 16 + fr) * 32 + fq * 8]);
    }
#pragma unroll
    for (int mi = 0; mi < 4; ++mi)
#pragma unroll
      for (int nj = 0; nj < 2; ++nj) {
        accg[mi][nj] = MFMA16(ag[mi], bg[nj], accg[mi][nj], 0, 0, 0);
        accu[mi][nj] = MFMA16(au[mi], bu[nj], accu[mi][nj], 0, 0, 0);
      }
    __syncthreads();
  }
#pragma unroll
  for (int mi = 0; mi < 4; ++mi)
#pragma unroll
    for (int r = 0; r < 4; ++r) {
      int row = m0 + wm + mi * 16 + fq * 4 + r;
      if (row < c) {
#pragma unroll
        for (int nj = 0; nj < 2; ++nj) {
          float g = accg[mi][nj][r];
          float u = accu[mi][nj][r];
          float s = g / (1.f + expf(-g)) * u;
          a[(long)(o + row) * cF + n0 + wn + nj * 16 + fr] = f2bf(s);
        }
      }
    }
}

// ---------------------------------------------------------------------------
// t3p[ks] = a @ udT^T (split-K=4, plain fp32 stores).  [4][ROWS][256].
// async staging, unpadded LDS [64][64], BK=64, clamped rows, 11 iters.
// grid = (16, 32, E): x = n(0..3) | ksp(0..3)<<2
// ---------------------------------------------------------------------------
__global__ __launch_bounds__(256) void k_t3(
    const unsigned short* __restrict__ a, const unsigned short* __restrict__ udT,
    float* __restrict__ t3p, const int* __restrict__ cnt,
    const int* __restrict__ off)
{
  __shared__ __align__(16) unsigned short As[64 * 64], Bs[64 * 64];
  const int e = blockIdx.z, c = cnt[e], o = off[e];
  const int m0 = blockIdx.y * 64;
  if (m0 >= c) return;
  const int n0 = (blockIdx.x & 3) * 64;
  const int ksp = blockIdx.x >> 2;                 // 0..3
  const int kbase = ksp * 704;
  const int tid = threadIdx.x;
  const int wid = tid >> 6, lane = tid & 63;
  const int sr8 = lane >> 3, sc = (lane & 7) * 8;
  const int ra0 = o + min(m0 + wid * 16 + sr8, c - 1);
  const int ra1 = o + min(m0 + wid * 16 + 8 + sr8, c - 1);
  const unsigned short* gA0 = a + (long)ra0 * cF + kbase + sc;
  const unsigned short* gA1 = a + (long)ra1 * cF + kbase + sc;
  const unsigned short* gB  = udT + (long)e * 256 * cF + (long)(n0 + wid * 16 + sr8) * cF + kbase + sc;
  unsigned short* lA = As + wid * 16 * 64;
  unsigned short* lB = Bs + wid * 16 * 64;
  const int wm = (wid >> 1) * 32, wn = (wid & 1) * 32;
  const int fr = lane & 15, fq = lane >> 4;
  float4v zf = {0.f, 0.f, 0.f, 0.f};
  float4v acc[2][2] = {{zf, zf}, {zf, zf}};
  for (int k0 = 0; k0 < 704; k0 += 64) {
    gld16(gA0 + k0, lA);
    gld16(gA1 + k0, lA + 8 * 64);
    gld16(gB + k0, lB);
    gld16(gB + (long)8 * cF + k0, lB + 8 * 64);
    __syncthreads();
#pragma unroll
    for (int ks = 0; ks < 2; ++ks) {
      short8 af[2], bf[2];
#pragma unroll
      for (int mi = 0; mi < 2; ++mi)
        af[mi] = *reinterpret_cast<const short8*>(
            &As[(wm + mi * 16 + fr) * 64 + ks * 32 + fq * 8]);
#pragma unroll
      for (int nj = 0; nj < 2; ++nj)
        bf[nj] = *reinterpret_cast<const short8*>(
            &Bs[(wn + nj * 16 + fr) * 64 + ks * 32 + fq * 8]);
#pragma unroll
      for (int mi = 0; mi < 2; ++mi)
#pragma unroll
        for (int nj = 0; nj < 2; ++nj)
          acc[mi][nj] = MFMA16(af[mi], bf[nj], acc[mi][nj], 0, 0, 0);
    }
    __syncthreads();
  }
  float* dstbase = t3p + (long)ksp * ROWS * 256;
#pragma unroll
  for (int mi = 0; mi < 2; ++mi)
#pragma unroll
    for (int r = 0; r < 4; ++r) {
      int row = m0 + wm + mi * 16 + fq * 4 + r;
      if (row < c) {
        float* dst = dstbase + (long)(o + row) * 256 + n0 + wn;
#pragma unroll
        for (int nj = 0; nj < 2; ++nj)
          dst[nj * 16 + fr] = acc[mi][nj][r];
      }
    }
}

// ---------------------------------------------------------------------------
// t3b bf16 = sum of 4 fp32 t3p partials (pure streaming). grid = 512.
// ---------------------------------------------------------------------------
__global__ __launch_bounds__(256) void k_red(
    const float* __restrict__ t3p, unsigned short* __restrict__ t3b)
{
  const long psz = (long)ROWS * 256;
  long i = ((long)blockIdx.x * 256 + threadIdx.x) * 8;
  float4 s0 = *reinterpret_cast<const float4*>(t3p + i);
  float4 s1 = *reinterpret_cast<const float4*>(t3p + i + 4);
#pragma unroll
  for (int q = 1; q < 4; ++q) {
    float4 a0 = *reinterpret_cast<const float4*>(t3p + q * psz + i);
    float4 a1 = *reinterpret_cast<const float4*>(t3p + q * psz + i + 4);
    s0.x += a0.x; s0.y += a0.y; s0.z += a0.z; s0.w += a0.w;
    s1.x += a1.x; s1.y += a1.y; s1.z += a1.z; s1.w += a1.w;
  }
  store_bf8(t3b + i, s0, s1);
}

// ---------------------------------------------------------------------------
// y = t3b @ vd2t^T   [rows x 1024] bf16, plain stores. K = 256.
// async staging (k_act pattern), unpadded LDS, BK=32. grid = (16, 16, E)
// ---------------------------------------------------------------------------
__global__ __launch_bounds__(256, 2) void k_y(
    const unsigned short* __restrict__ t3b, const unsigned short* __restrict__ vd2t,
    unsigned short* __restrict__ y, const int* __restrict__ cnt,
    const int* __restrict__ off)
{
  __shared__ __align__(16) unsigned short As[128 * 32], Bs[64 * 32];
  const int e = blockIdx.z, c = cnt[e], o = off[e];
  const int m0 = blockIdx.y * 128;
  if (m0 >= c) return;
  const int n0 = blockIdx.x * 64;
  const int tid = threadIdx.x;
  const int wid = tid >> 6, lane = tid & 63;
  const int sr16 = lane >> 2, sc = (lane & 3) * 8;
  const int ra0 = o + min(m0 + wid * 32 + sr16, c - 1);
  const int ra1 = o + min(m0 + wid * 32 + 16 + sr16, c - 1);
  const unsigned short* gA0 = t3b + (long)ra0 * 256 + sc;
  const unsigned short* gA1 = t3b + (long)ra1 * 256 + sc;
  const unsigned short* gB  = vd2t + (long)e * cH * 256 + (long)(n0 + wid * 16 + sr16) * 256 + sc;
  unsigned short* lA = As + wid * 32 * 32;
  unsigned short* lB = Bs + wid * 16 * 32;
  const int wm = (wid >> 1) * 64, wn = (wid & 1) * 32;
  const int fr = lane & 15, fq = lane >> 4;
  float4v zf = {0.f, 0.f, 0.f, 0.f};
  float4v acc[4][2];
#pragma unroll
  for (int i = 0; i < 4; ++i) { acc[i][0] = zf; acc[i][1] = zf; }
  for (int k0 = 0; k0 < 256; k0 += 32) {
    gld16(gA0 + k0, lA);
    gld16(gA1 + k0, lA + 16 * 32);
    gld16(gB + k0, lB);
    __syncthreads();
    short8 af[4], bf[2];
#pragma unroll
    for (int mi = 0; mi < 4; ++mi)
      af[mi] = *reinterpret_cast<const short8*>(&As[(wm + mi * 16 + fr) * 32 + fq * 8]);
#pragma unroll
    for (int nj = 0; nj < 2; ++nj)
      bf[nj] = *reinterpret_cast<const short8*>(&Bs[(wn + nj * 16 + fr) * 32 + fq * 8]);
#pragma unroll
    for (int mi = 0; mi < 4; ++mi)
#pragma unroll
      for (int nj = 0; nj < 2; ++nj)
        acc[mi][nj] = MFMA16(af[mi], bf[nj], acc[mi][nj], 0, 0, 0);
    __syncthreads();
  }
#pragma unroll
  for (int mi = 0; mi < 4; ++mi)
#pragma unroll
    for (int r = 0; r < 4; ++r) {
      int row = m0 + wm + mi * 16 + fq * 4 + r;
      if (row < c) {
#pragma unroll
        for (int nj = 0; nj < 2; ++nj)
          y[(long)(o + row) * cH + n0 + wn + nj * 16 + fr] = f2bf(acc[mi][nj][r]);
      }
    }
}

// ---------------------------------------------------------------------------
// out[t] = w0 * y[rowmap[2t]] + w1 * y[rowmap[2t+1]]   (pure write, no zero)
// ---------------------------------------------------------------------------
__global__ __launch_bounds__(256) void k_combine(
    const unsigned short* __restrict__ y, const float* __restrict__ wt,
    const int* __restrict__ rowmap, float* __restrict__ out)
{
  const int tid = threadIdx.x;
  const int t = blockIdx.x * 2 + (tid >> 7);
  const int h = (tid & 127) * 8;
  const int r0 = rowmap[2 * t], r1 = rowmap[2 * t + 1];
  const float w0 = wt[2 * t], w1 = wt[2 * t + 1];
  union { uint4 v; unsigned short s[8]; } ua, ub;
  ua.v = *reinterpret_cast<const uint4*>(y + (long)r0 * cH + h);
  ub.v = *reinterpret_cast<const uint4*>(y + (long)r1 * cH + h);
  float o[8];
#pragma unroll
  for (int i = 0; i < 8; ++i)
    o[i] = w0 * bf2f(ua.s[i]) + w1 * bf2f(ub.s[i]);
  float* dst = out + (long)t * cH + h;
  *reinterpret_cast<float4*>(dst)     = make_float4(o[0], o[1], o[2], o[3]);
  *reinterpret_cast<float4*>(dst + 4) = make_float4(o[4], o[5], o[6], o[7]);
}

// ---------------------------------------------------------------------------
extern "C" void kernel_launch(void* const* d_in, const int* in_sizes, int n_in,
                              void* d_out, int out_size, void* d_ws, size_t ws_size,
                              hipStream_t stream)
{
  const float* x  = (const float*)d_in[0];
  const float* gw = (const float*)d_in[1];
  const float* Ug = (const float*)d_in[2];
  const float* Cg = (const float*)d_in[3];
  const float* Vg = (const float*)d_in[4];
  const float* Uu = (const float*)d_in[5];
  const float* Cu = (const float*)d_in[6];
  const float* Vu = (const float*)d_in[7];
  const float* Ud = (const float*)d_in[8];
  const float* Cd = (const float*)d_in[9];
  const float* Vd = (const float*)d_in[10];
  float* out = (float*)d_out;

  // workspace layout (~79 MiB peak, with aliasing)
  char* w = (char*)d_ws;
  // region 0: [vgT 11.53 | b1t 8.39] phase-1; phase-2: t3p (16 MiB fp32 x4
  // partials) + t3b (2 MiB bf16 reduced) both alias it (18.87 <= 19.92 MB)
  unsigned short* vgT = (unsigned short*)w;
  float*          t3p = (float*)w;
  unsigned short* t3b = (unsigned short*)(w + (long)4 * ROWS * 256 * 4);
  w += (long)cE * cF * 256 * 2;                                               // 11.53
  unsigned short* b1t = (unsigned short*)w;  w += (long)cE * 512 * 1024 * 2;  // 8.39
  unsigned short* vd2t = (unsigned short*)w; w += (long)cE * cH * 256 * 2;    // 4.19
  // vuT phase-1; yb (8.39) aliases it in phase 2
  unsigned short* vuT = (unsigned short*)w;
  unsigned short* yb  = (unsigned short*)w;  w += (long)cE * cF * 256 * 2;    // 11.53
  unsigned short* udT = (unsigned short*)w;  w += (long)cE * 256 * cF * 2;    // 11.53
  // VdT consumed by fold 3; xb (bf16 x, 4.19 MB) aliases it afterwards
  unsigned short* VdT = (unsigned short*)w;
  unsigned short* xb  = (unsigned short*)w;  w += (long)cE * cH * 256 * 2;    // 4.19
  unsigned short* CgT = (unsigned short*)w;  w += (long)cR * cR * 2;          // 0.13
  unsigned short* CuT = (unsigned short*)w;  w += (long)cR * cR * 2;          // 0.13
  unsigned short* t1  = (unsigned short*)w;  w += (long)ROWS * 512 * 2;       // 4.19
  unsigned short* ab  = (unsigned short*)w;  w += (long)ROWS * cF * 2;        // 23.07
  float* wt   = (float*)w; w += ROWS * 4;
  int* et     = (int*)w; w += ROWS * 4;
  int* rowmap = (int*)w; w += ROWS * 4;
  int* tok    = (int*)w; w += ROWS * 4;
  int* cnt = (int*)w; w += cE * 4;
  int* off = (int*)w; w += cE * 4;

  // 1. all transposes (fp32 -> bf16) in one launch
  k_tconv_all<<<dim3(TCONV_BLOCKS), dim3(256), 0, stream>>>(
      Cg, CgT, Cu, CuT, Vd, VdT, Vg, vgT, Vu, vuT, Ud, udT);
  // 2. MFMA folds (all K=256): merged gate+up b1t fold, then vd2t fold
  k_foldm2<<<dim3(cH / 64, cR / 128, 16), dim3(256), 0, stream>>>(
      CgT, CuT, Ug, Uu, b1t);
  k_foldm<<<dim3(cR / 64, cH / 128, cE), dim3(256), 0, stream>>>(
      VdT, (long)cH * cR, Cd, 0, vd2t, (long)cH * 256, cR);
  // 3. gating + x->bf16 (xb overwrites dead VdT) + lists
  k_gating<<<dim3(cT / 4), dim3(256), 0, stream>>>(x, gw, xb, et, wt);
  k_lists<<<dim3(1), dim3(256), 0, stream>>>(et, rowmap, tok, cnt, off);
  // 4. COMPACT t1 GEMM (gathered A rows, per-expert B) — replaces dense t1d
  k_t1c<<<dim3(8, cT / 128, cE), dim3(256), 0, stream>>>(xb, b1t, t1, tok, cnt, off);
  // 5. a = silu(t1g @ Vg) * (t1u @ Vu)  (async staging)
  k_act<<<dim3(cF / 64, cT / 128, cE), dim3(256), 0, stream>>>(t1, vgT, vuT, ab, cnt, off);
  // 6. t3p = a @ Ud (split-K=4, async staging; aliases dead vgT+b1t)
  k_t3<<<dim3(16, cT / 64, cE), dim3(256), 0, stream>>>(ab, udT, t3p, cnt, off);
  // 7. t3b = bf16(sum of 4 partials)
  k_red<<<dim3(ROWS * 256 / (256 * 8)), dim3(256), 0, stream>>>(t3p, t3b);
  // 8. y = t3b @ Vd2 (async staging, plain bf16 stores; aliases dead vuT)
  k_y<<<dim3(cH / 64, cT / 128, cE), dim3(256), 0, stream>>>(t3b, vd2t, yb, cnt, off);
  // 9. out = w0*y[r0] + w1*y[r1]
  k_combine<<<dim3(cT / 2), dim3(256), 0, stream>>>(yb, wt, rowmap, out);
}